// Round 6
// baseline (258.026 us; speedup 1.0000x reference)
//
#include <hip/hip_runtime.h>

// B=8, N=196, C=512, NC=10, H=8, HD=64, SCALE=0.125
//
// Pipeline (bf16 MFMA 16x16x32, fp32 accum). MFMA operand fragments are loaded
// DIRECTLY from global memory (16B contiguous per lane in these layouts); LDS is
// used only for the C-layout -> A-layout transform of S tiles.
//   pre:    x,anchors -> bf16; Wqk,Wqk2,Wv,Wproj -> bf16 transposed [n][k]
//   proj5:  XQ,XQ2 (1568x512), AQ,AQ2 (1960x512), XVT[b][512][208] = (x_b@Wv)^T
//   rv2:    wrvT[bch][dd][264] = w[b,h,c] * (relu(+S*k2@q2^T) @ v)^T, j>=196 -> 0
//   attn:   left = relu(-S*q@k^T) -> d_out (fp32); out1 += left @ wrv (fp32 atomics)
//   final:  out = out1 @ Wproj + bproj
//
// ws layout (bytes), total 39,477,248:
#define OFF_XB     0u          // 1,605,632
#define OFF_AB     1605632u    // 2,007,040
#define OFF_WQKT   3612672u    // 524,288
#define OFF_WQK2T  4136960u
#define OFF_WVT    4661248u
#define OFF_WPROJT 5185536u
#define OFF_XQ     5709824u    // 1,605,632
#define OFF_XQ2    7315456u
#define OFF_AQ     8921088u    // 2,007,040
#define OFF_AQ2    10928128u
#define OFF_XVT    12935168u   // 8*512*208*2 = 1,703,936
#define OFF_WRVT   14639104u   // 640*64*264*2 = 21,626,880
#define OFF_OUT1   36265984u   // 1568*512*4 = 3,211,264

typedef __attribute__((ext_vector_type(8))) short bf16x8;
typedef __attribute__((ext_vector_type(4))) float f32x4;
#define MFMA(a, b, c) __builtin_amdgcn_mfma_f32_16x16x32_bf16((a), (b), (c), 0, 0, 0)

__device__ __forceinline__ unsigned short f2bf(float x) {
  unsigned u = __builtin_bit_cast(unsigned, x);
  u += 0x7fffu + ((u >> 16) & 1u);
  return (unsigned short)(u >> 16);
}

__device__ __forceinline__ void gl_lds16(const void* g, void* l) {
  __builtin_amdgcn_global_load_lds(
      (const __attribute__((address_space(1))) unsigned int*)g,
      (__attribute__((address_space(3))) unsigned int*)l, 16, 0, 0);
}

// 64x64 bf16 -> LDS [64][72] (final_gemm W staging only).
__device__ __forceinline__ void stage64(const unsigned short* g0, int stride,
                                        unsigned short (*T)[72], int tid) {
  int wv = tid >> 6;
  char* base = (char*)&T[0][0];
#pragma unroll
  for (int i = 0; i < 2; i++) {
    int k = i * 256 + tid;
    int r = k / 9, c = k - r * 9;
    gl_lds16(g0 + (size_t)r * stride + (c << 3), base + (((i << 2) + wv) << 10));
  }
  if (tid < 64) {
    int k = 512 + tid;
    int r = k / 9, c = k - r * 9;
    gl_lds16(g0 + (size_t)r * stride + (c << 3), base + 8192);
  }
}

// ---- pre: bf16 conversions + W transposes ----
__global__ __launch_bounds__(256) void pre_kernel(const float* __restrict__ x, const float* __restrict__ anchors,
                                                  const float* __restrict__ Wqk, const float* __restrict__ Wqk2,
                                                  const float* __restrict__ Wv, const float* __restrict__ Wproj,
                                                  char* __restrict__ ws) {
  int tid = threadIdx.x;
  if (blockIdx.x < 1764) {  // convert x (802816) + anchors (1003520) -> XB/AB (contiguous)
    int base = blockIdx.x * 1024 + (tid << 2);
    float4 f = (base < 802816) ? *(const float4*)(x + base)
                               : *(const float4*)(anchors + (base - 802816));
    unsigned short s[4] = {f2bf(f.x), f2bf(f.y), f2bf(f.z), f2bf(f.w)};
    *(uint2*)((unsigned short*)(ws + OFF_XB) + base) = *(uint2*)s;
    return;
  }
  __shared__ unsigned short Ls[64][72];
  int idx = blockIdx.x - 1764;
  int wsel = idx >> 6, t = idx & 63;
  int k0 = (t >> 3) << 6, n0 = (t & 7) << 6;
  const float* W;
  unsigned short* WT;
  switch (wsel) {
    case 0:  W = Wqk;   WT = (unsigned short*)(ws + OFF_WQKT);   break;
    case 1:  W = Wqk2;  WT = (unsigned short*)(ws + OFF_WQK2T);  break;
    case 2:  W = Wv;    WT = (unsigned short*)(ws + OFF_WVT);    break;
    default: W = Wproj; WT = (unsigned short*)(ws + OFF_WPROJT); break;
  }
  {
    int r = tid >> 2, seg = (tid & 3) << 4;
    const float* p = W + (size_t)(k0 + r) * 512 + n0 + seg;
    float4 f0 = *(const float4*)p, f1 = *(const float4*)(p + 4);
    float4 f2 = *(const float4*)(p + 8), f3 = *(const float4*)(p + 12);
    unsigned short s[16] = {f2bf(f0.x), f2bf(f0.y), f2bf(f0.z), f2bf(f0.w),
                            f2bf(f1.x), f2bf(f1.y), f2bf(f1.z), f2bf(f1.w),
                            f2bf(f2.x), f2bf(f2.y), f2bf(f2.z), f2bf(f2.w),
                            f2bf(f3.x), f2bf(f3.y), f2bf(f3.z), f2bf(f3.w)};
    *(uint4*)&Ls[r][seg] = *(uint4*)s;
    *(uint4*)&Ls[r][seg + 8] = *(uint4*)(s + 8);
  }
  __syncthreads();
  {
    int r = tid >> 2, seg = (tid & 3) << 4;
    unsigned short s[16];
#pragma unroll
    for (int u = 0; u < 16; u++) s[u] = Ls[seg + u][r];
    unsigned short* dst = WT + (size_t)(n0 + r) * 512 + k0 + seg;
    *(uint4*)dst = *(uint4*)s;
    *(uint4*)(dst + 8) = *(uint4*)(s + 8);
  }
}

// ---- proj5: LDS-free, barrier-free 128x128-tile GEMMs, frags direct from global ----
// z=0..3: XQ/XQ2/AQ/AQ2 = {XB,AB} @ {Wqk,Wqk2}^T.  z=4: XVT[b][512][208] = WVT @ XB_b^T.
__global__ __launch_bounds__(256) void proj5(char* __restrict__ ws) {
  const unsigned short *A, *Bp;
  unsigned short* O;
  int M, Nmask, ostride, row0, col0;
  int z = blockIdx.z;
  if (z < 4) {
    if (z < 2 && blockIdx.x >= 13) return;
    row0 = blockIdx.x << 7;
    col0 = blockIdx.y << 7;
    ostride = 512; Nmask = 512;
    A = (const unsigned short*)(ws + (z < 2 ? OFF_XB : OFF_AB));
    M = (z < 2) ? 1568 : 1960;
    Bp = (const unsigned short*)(ws + ((z & 1) ? OFF_WQK2T : OFF_WQKT));
    O = (unsigned short*)(ws + (z == 0 ? OFF_XQ : z == 1 ? OFF_XQ2 : z == 2 ? OFF_AQ : OFF_AQ2));
  } else {
    int b = blockIdx.x >> 1;
    row0 = blockIdx.y << 7;            // dd-row 0..511
    col0 = (blockIdx.x & 1) << 7;      // 0/128 within 208 tokens
    A = (const unsigned short*)(ws + OFF_WVT);
    Bp = (const unsigned short*)(ws + OFF_XB) + (size_t)(b * 196) * 512;
    O = (unsigned short*)(ws + OFF_XVT) + (size_t)b * 512 * 208;
    M = 512; Nmask = 208; ostride = 208;
  }
  int tid = threadIdx.x;
  int w = tid >> 6, lm = tid & 15, lq = (tid >> 4) & 3;
  int h1 = w & 1, h2 = w >> 1;
  const unsigned short* ar[4];
  const unsigned short* br[4];
#pragma unroll
  for (int mi = 0; mi < 4; mi++)
    ar[mi] = A + (size_t)(row0 + (h1 << 6) + (mi << 4) + lm) * 512 + (lq << 3);
#pragma unroll
  for (int ni = 0; ni < 4; ni++)
    br[ni] = Bp + (size_t)(col0 + (h2 << 6) + (ni << 4) + lm) * 512 + (lq << 3);
  f32x4 acc[4][4] = {};
#pragma unroll 4
  for (int kk = 0; kk < 16; kk++) {
    bf16x8 bfr[4], afr[4];
#pragma unroll
    for (int ni = 0; ni < 4; ni++) bfr[ni] = *(const bf16x8*)(br[ni] + (kk << 5));
#pragma unroll
    for (int mi = 0; mi < 4; mi++) afr[mi] = *(const bf16x8*)(ar[mi] + (kk << 5));
#pragma unroll
    for (int mi = 0; mi < 4; mi++)
#pragma unroll
      for (int ni = 0; ni < 4; ni++) acc[mi][ni] = MFMA(afr[mi], bfr[ni], acc[mi][ni]);
  }
#pragma unroll
  for (int mi = 0; mi < 4; mi++)
#pragma unroll
    for (int r = 0; r < 4; r++) {
      int row = row0 + (h1 << 6) + (mi << 4) + (lq << 2) + r;
      if (row < M) {
#pragma unroll
        for (int ni = 0; ni < 4; ni++) {
          int col = col0 + (h2 << 6) + (ni << 4) + lm;
          if (col < Nmask) O[(size_t)row * ostride + col] = f2bf(acc[mi][ni][r]);
        }
      }
    }
}

// ---- rv2: wrvT[bch][dd][264] = w * (relu(0.125*k2@q2^T) @ v)^T ----
__global__ __launch_bounds__(256) void rv2(char* __restrict__ ws, const float* __restrict__ weights) {
  const unsigned short* xq2 = (const unsigned short*)(ws + OFF_XQ2);
  const unsigned short* aq2 = (const unsigned short*)(ws + OFF_AQ2);
  const unsigned short* xvt = (const unsigned short*)(ws + OFF_XVT);
  unsigned short* wrvt      = (unsigned short*)(ws + OFF_WRVT);
  __shared__ unsigned short Ss[128][136];   // 34,816 B
  int jblk = blockIdx.x, bch = blockIdx.y;  // jblk: anchor 128-block
  int h = bch & 7, bc = bch >> 3;
  int c = bc % 10, b = bc / 10;
  int bh = b * 8 + h;
  int tid = threadIdx.x;
  int w = tid >> 6, lm = tid & 15, lq = (tid >> 4) & 3;
  int h1 = w & 1, h2 = w >> 1;
  float wc = weights[bh * 10 + c];
  int ja0 = jblk << 7;

  // A-frags: anchors (k2), persistent
  bf16x8 kf[4][2];
#pragma unroll
  for (int mi = 0; mi < 4; mi++) {
    const unsigned short* p =
        aq2 + (size_t)(c * 196 + ja0 + (h1 << 6) + (mi << 4) + lm) * 512 + (h << 6) + (lq << 3);
#pragma unroll
    for (int kk = 0; kk < 2; kk++) kf[mi][kk] = *(const bf16x8*)(p + (kk << 5));
  }

  f32x4 acc[4][2] = {};
  for (int mt = 0; mt < 2; mt++) {  // x-token 128-blocks
    int m0 = mt << 7;
    // S2 = k2 @ q2^T : B-frags direct from xq2
    f32x4 s[4][4] = {};
#pragma unroll
    for (int kk = 0; kk < 2; kk++) {
      bf16x8 bfr[4];
#pragma unroll
      for (int ni = 0; ni < 4; ni++)
        bfr[ni] = *(const bf16x8*)(xq2 +
            (size_t)(b * 196 + m0 + (h2 << 6) + (ni << 4) + lm) * 512 + (h << 6) + (kk << 5) + (lq << 3));
#pragma unroll
      for (int mi = 0; mi < 4; mi++)
#pragma unroll
        for (int ni = 0; ni < 4; ni++) s[mi][ni] = MFMA(kf[mi][kk], bfr[ni], s[mi][ni]);
    }
    __syncthreads();  // prev PV done reading Ss
    // relu + bf16 -> Ss (A-layout source), zero cols m>=196
#pragma unroll
    for (int ni = 0; ni < 4; ni++) {
      int ml = (h2 << 6) + (ni << 4) + lm;
      bool ok = (m0 + ml) < 196;
#pragma unroll
      for (int mi = 0; mi < 4; mi++)
#pragma unroll
        for (int r = 0; r < 4; r++) {
          float v = ok ? fmaxf(0.125f * s[mi][ni][r], 0.f) : 0.f;
          Ss[(h1 << 6) + (mi << 4) + (lq << 2) + r][ml] = f2bf(v);
        }
    }
    __syncthreads();
    // PV2: acc += Ss @ V ; B-frags direct from XVT[b][dd][token]
#pragma unroll
    for (int kkp = 0; kkp < 4; kkp++) {
      bf16x8 bfr[2];
#pragma unroll
      for (int ni = 0; ni < 2; ni++) {
        int ddl = (h2 << 5) + (ni << 4) + lm;
        bfr[ni] = *(const bf16x8*)(xvt +
            ((size_t)(b * 512) + (h << 6) + ddl) * 208 + m0 + (kkp << 5) + (lq << 3));
      }
#pragma unroll
      for (int mi = 0; mi < 4; mi++) {
        bf16x8 afr = *(const bf16x8*)&Ss[(h1 << 6) + (mi << 4) + lm][(kkp << 5) + (lq << 3)];
#pragma unroll
        for (int ni = 0; ni < 2; ni++) acc[mi][ni] = MFMA(afr, bfr[ni], acc[mi][ni]);
      }
    }
  }
  __syncthreads();  // PV reads done -> reuse Ss[0..63] as [dd][j] transpose buffer
#pragma unroll
  for (int mi = 0; mi < 4; mi++)
#pragma unroll
    for (int ni = 0; ni < 2; ni++)
#pragma unroll
      for (int r = 0; r < 4; r++)
        Ss[(h2 << 5) + (ni << 4) + lm][(h1 << 6) + (mi << 4) + (lq << 2) + r] =
            f2bf(wc * acc[mi][ni][r]);
  __syncthreads();
  {
    int dd = tid >> 2, seg = (tid & 3) << 5;
    unsigned short vbuf[32];
#pragma unroll
    for (int u = 0; u < 32; u++) {
      int j = ja0 + seg + u;
      vbuf[u] = (j < 196) ? Ss[dd][seg + u] : (unsigned short)0;
    }
    unsigned short* dst = wrvt + ((size_t)bch * 64 + dd) * 264 + ja0 + seg;
#pragma unroll
    for (int u = 0; u < 4; u++) *(uint4*)(dst + (u << 3)) = *(uint4*)&vbuf[u << 3];
  }
}

// ---- attn_left: left = relu(-0.125*q@k^T) -> d_out; out1 += left @ wrv (atomics) ----
__global__ __launch_bounds__(256) void attn_left(char* __restrict__ ws, float* __restrict__ left,
                                                 float* __restrict__ out1) {
  const unsigned short* xq   = (const unsigned short*)(ws + OFF_XQ);
  const unsigned short* aq   = (const unsigned short*)(ws + OFF_AQ);
  const unsigned short* wrvt = (const unsigned short*)(ws + OFF_WRVT);
  __shared__ unsigned short Ss[128][136];   // 34,816 B
  int iblk = blockIdx.x, bch = blockIdx.y;
  int h = bch & 7, bc = bch >> 3;
  int c = bc % 10, b = bc / 10;
  int bh = b * 8 + h;
  int tid = threadIdx.x;
  int w = tid >> 6, lm = tid & 15, lq = (tid >> 4) & 3;
  int h1 = w & 1, h2 = w >> 1;
  int i0 = iblk << 7;

  // A-frags: q rows, persistent
  bf16x8 qf[4][2];
#pragma unroll
  for (int mi = 0; mi < 4; mi++) {
    const unsigned short* p =
        xq + (size_t)(b * 196 + i0 + (h1 << 6) + (mi << 4) + lm) * 512 + (h << 6) + (lq << 3);
#pragma unroll
    for (int kk = 0; kk < 2; kk++) qf[mi][kk] = *(const bf16x8*)(p + (kk << 5));
  }

  f32x4 acc[4][2] = {};
  size_t lbase = (size_t)bch * (196 * 196);
  for (int jt = 0; jt < 2; jt++) {
    int j0 = jt << 7;
    // S = q @ k^T : B-frags direct from aq
    f32x4 s[4][4] = {};
#pragma unroll
    for (int kk = 0; kk < 2; kk++) {
      bf16x8 bfr[4];
#pragma unroll
      for (int ni = 0; ni < 4; ni++)
        bfr[ni] = *(const bf16x8*)(aq +
            (size_t)(c * 196 + j0 + (h2 << 6) + (ni << 4) + lm) * 512 + (h << 6) + (kk << 5) + (lq << 3));
#pragma unroll
      for (int mi = 0; mi < 4; mi++)
#pragma unroll
        for (int ni = 0; ni < 4; ni++) s[mi][ni] = MFMA(qf[mi][kk], bfr[ni], s[mi][ni]);
    }
    __syncthreads();  // prev PV done reading Ss
    // relu(-S) -> left (fp32, masked) + Ss (bf16)
#pragma unroll
    for (int mi = 0; mi < 4; mi++)
#pragma unroll
      for (int r = 0; r < 4; r++) {
        int il = (h1 << 6) + (mi << 4) + (lq << 2) + r;
        int i = i0 + il;
        bool iok = i < 196;
#pragma unroll
        for (int ni = 0; ni < 4; ni++) {
          int jl = (h2 << 6) + (ni << 4) + lm;
          float v = fmaxf(-0.125f * s[mi][ni][r], 0.f);
          Ss[il][jl] = f2bf(v);
          int j = j0 + jl;
          if (iok && j < 196) left[lbase + (size_t)i * 196 + j] = v;
        }
      }
    __syncthreads();
    // PV: acc += Ss @ wrv ; B-frags direct from wrvT (zero-padded past 196)
#pragma unroll
    for (int kkp = 0; kkp < 4; kkp++) {
      bf16x8 bfr[2];
#pragma unroll
      for (int ni = 0; ni < 2; ni++) {
        int ddl = (h2 << 5) + (ni << 4) + lm;
        bfr[ni] = *(const bf16x8*)(wrvt +
            ((size_t)bch * 64 + ddl) * 264 + j0 + (kkp << 5) + (lq << 3));
      }
#pragma unroll
      for (int mi = 0; mi < 4; mi++) {
        bf16x8 afr = *(const bf16x8*)&Ss[(h1 << 6) + (mi << 4) + lm][(kkp << 5) + (lq << 3)];
#pragma unroll
        for (int ni = 0; ni < 2; ni++) acc[mi][ni] = MFMA(afr, bfr[ni], acc[mi][ni]);
      }
    }
  }
#pragma unroll
  for (int mi = 0; mi < 4; mi++)
#pragma unroll
    for (int r = 0; r < 4; r++) {
      int i = i0 + (h1 << 6) + (mi << 4) + (lq << 2) + r;
      if (i < 196) {
#pragma unroll
        for (int ni = 0; ni < 2; ni++) {
          int dd = (h2 << 5) + (ni << 4) + lm;
          atomicAdd(&out1[((size_t)bh * 196 + i) * 64 + dd], acc[mi][ni][r]);
        }
      }
    }
}

// ---- final: out[1568,512] = out1(f32) @ WprojT^T + bproj ----
__global__ __launch_bounds__(256) void final_gemm(const float* __restrict__ A, const unsigned short* __restrict__ WT,
                                                  const float* __restrict__ bias, float* __restrict__ out) {
  __shared__ unsigned short As[64][72];
  __shared__ unsigned short Ws[64][72];
  int row0 = blockIdx.x << 6;
  int col0 = blockIdx.y << 6;
  int tid = threadIdx.x;
  int w = tid >> 6, lm = tid & 15, lq = (tid >> 4) & 3;
  f32x4 acc[4] = {};
  for (int k0 = 0; k0 < 512; k0 += 64) {
    __syncthreads();
    {  // convert-stage A (f32 -> bf16), zero rows >= 1568
      int r = tid >> 2, c0 = (tid & 3) << 4;
      float4 f0, f1, f2, f3;
      if (row0 + r < 1568) {
        const float* p = A + (size_t)(row0 + r) * 512 + k0 + c0;
        f0 = *(const float4*)p;       f1 = *(const float4*)(p + 4);
        f2 = *(const float4*)(p + 8); f3 = *(const float4*)(p + 12);
      } else {
        f0 = f1 = f2 = f3 = make_float4(0.f, 0.f, 0.f, 0.f);
      }
      unsigned short s[16] = {f2bf(f0.x), f2bf(f0.y), f2bf(f0.z), f2bf(f0.w),
                              f2bf(f1.x), f2bf(f1.y), f2bf(f1.z), f2bf(f1.w),
                              f2bf(f2.x), f2bf(f2.y), f2bf(f2.z), f2bf(f2.w),
                              f2bf(f3.x), f2bf(f3.y), f2bf(f3.z), f2bf(f3.w)};
      *(uint4*)&As[r][c0] = *(uint4*)s;
      *(uint4*)&As[r][c0 + 8] = *(uint4*)(s + 8);
    }
    stage64(WT + (size_t)col0 * 512 + k0, 512, Ws, tid);
    __syncthreads();
#pragma unroll
    for (int kk = 0; kk < 2; kk++) {
      bf16x8 bf = *(const bf16x8*)&Ws[(w << 4) + lm][(kk << 5) + (lq << 3)];
#pragma unroll
      for (int mi = 0; mi < 4; mi++) {
        bf16x8 af = *(const bf16x8*)&As[(mi << 4) + lm][(kk << 5) + (lq << 3)];
        acc[mi] = MFMA(af, bf, acc[mi]);
      }
    }
  }
  int ncol = col0 + (w << 4) + lm;
  float bv = bias[ncol];
#pragma unroll
  for (int mi = 0; mi < 4; mi++)
#pragma unroll
    for (int r2 = 0; r2 < 4; r2++) {
      int row = row0 + (mi << 4) + (lq << 2) + r2;
      if (row < 1568) out[(size_t)row * 512 + ncol] = acc[mi][r2] + bv;
    }
}

extern "C" void kernel_launch(void* const* d_in, const int* in_sizes, int n_in,
                              void* d_out, int out_size, void* d_ws, size_t ws_size,
                              hipStream_t stream) {
  (void)in_sizes; (void)n_in; (void)out_size; (void)ws_size;
  const float* x       = (const float*)d_in[0];
  const float* anchors = (const float*)d_in[1];
  const float* weights = (const float*)d_in[2];
  const float* Wqk     = (const float*)d_in[3];
  const float* Wqk2    = (const float*)d_in[4];
  const float* Wv      = (const float*)d_in[5];
  const float* Wproj   = (const float*)d_in[6];
  const float* bproj   = (const float*)d_in[7];
  char* ws = (char*)d_ws;                     // 39,477,248 bytes used
  float* out  = (float*)d_out;
  float* left = out + 802816;
  float* out1 = (float*)(ws + OFF_OUT1);

  dim3 blk(256);
  hipMemsetAsync(out1, 0, 3211264, stream);
  pre_kernel<<<dim3(2020), blk, 0, stream>>>(x, anchors, Wqk, Wqk2, Wv, Wproj, ws);
  proj5<<<dim3(16, 4, 5), blk, 0, stream>>>(ws);
  rv2<<<dim3(2, 640), blk, 0, stream>>>(ws, weights);
  attn_left<<<dim3(2, 640), blk, 0, stream>>>(ws, left, out1);
  final_gemm<<<dim3(25, 8), blk, 0, stream>>>(out1, (const unsigned short*)(ws + OFF_WPROJT), bproj, out);
}